// Round 1
// baseline (1007.494 us; speedup 1.0000x reference)
//
#include <hip/hip_runtime.h>
#include <stdint.h>

// ============================================================================
// EncoderLayer (gather -> FC+BN+PReLU -> FC+BN -> pair-max | sample branch ->
// where(replaced)) fused for MI355X.
//
// Math notes (all verified against the reference):
//  * BN with batch stats cancels the Linear bias entirely (b1,b2,sb1,sb2 unused).
//  * Layer-1 BN folds into W1 (W1' = W1*s, b1' = be1 - m1*s1) AFTER stats1.
//  * Layer-2 BN is applied AFTER the pairwise max (g2=ones>0, affine monotone),
//    so pass-B stores RAW y2 (maxpair -> d_out, sample y2 -> ws).
//  * Matmuls run as bf16 MFMA with hi/lo split (3 MFMA terms) ~ fp32 accurate.
//
// Kernel DAG (8 launches, all on `stream`):
//  k_init -> k_pass<br,STATS> x2 -> k_fold1 -> k_pass<br,MAIN> x2 -> k_fold2 -> k_final
//
// Assumptions to re-check from bench feedback:
//  * `replaced` arrives as int32 (harness "integer -> const int*" rule).
//  * ws_size >= ~135 MB (y2s 134.2MB + ~0.4MB small buffers).
// ============================================================================

typedef __bf16 bf8_t __attribute__((ext_vector_type(8)));
typedef float  f4_t  __attribute__((ext_vector_type(4)));

#define DEVI static __device__ __forceinline__

DEVI unsigned short f2bf(float x){             // RNE f32 -> bf16 bits
  union { float f; unsigned u; } c; c.f = x;
  unsigned r = (c.u + 0x7FFFu + ((c.u >> 16) & 1u)) >> 16;
  return (unsigned short)r;
}
DEVI float bf2f(unsigned short h){
  union { unsigned u; float f; } c; c.u = ((unsigned)h) << 16; return c.f;
}
DEVI f4_t MFMA(uint4 a, uint4 b, f4_t c){
  return __builtin_amdgcn_mfma_f32_16x16x32_bf16(
      __builtin_bit_cast(bf8_t, a), __builtin_bit_cast(bf8_t, b), c, 0, 0, 0);
}
DEVI float wave16_sum(float v){                // reduce across lane bits 0..3
  v += __shfl_xor(v, 1); v += __shfl_xor(v, 2);
  v += __shfl_xor(v, 4); v += __shfl_xor(v, 8);
  return v;
}

// ---------------------------------------------------------------------------
// k_init: zero stat slots; split raw W1/W2 (both branches) into bf16 hi/lo.
// ---------------------------------------------------------------------------
__global__ void k_init(const float* __restrict__ W1, const float* __restrict__ sW1,
                       const float* __restrict__ W2, const float* __restrict__ sW2,
                       unsigned short* __restrict__ W1rhi, unsigned short* __restrict__ W1rlo,
                       unsigned short* __restrict__ W2rhi, unsigned short* __restrict__ W2rlo,
                       float* __restrict__ slots1, float* __restrict__ slots2)
{
  int i = blockIdx.x * 256 + threadIdx.x;
  if (i < 32768)       slots1[i] = 0.f;            // [2][64][2][128]
  else if (i < 49152)  slots2[i - 32768] = 0.f;    // [2][64][2][64]
  int j = i - 49152;                               // W1 split: [2][128][64]
  if (j >= 0 && j < 16384){
    float v = (j < 8192) ? W1[j] : sW1[j - 8192];
    unsigned short h = f2bf(v);
    W1rhi[j] = h; W1rlo[j] = f2bf(v - bf2f(h));
  }
  int k = i - 65536;                               // W2 split: [2][64][128]
  if (k >= 0 && k < 16384){
    float v = (k < 8192) ? W2[k] : sW2[k - 8192];
    unsigned short h = f2bf(v);
    W2rhi[k] = h; W2rlo[k] = f2bf(v - bf2f(h));
  }
}

// ---------------------------------------------------------------------------
// k_pass<BRANCH, MAIN>: the workhorse. 256 threads, 64 gathered rows / block.
//   MAIN=false (stats1): y1_raw = x@W1^T (split), accumulate per-ch sum/sumsq.
//   MAIN=true: y1' = x@W1f^T + b1' -> PReLU -> h (hi/lo in LDS) -> y2 = h@W2^T,
//              accumulate y2 sum/sumsq, store raw (br0: pair-max -> d_out,
//              br1: y2 -> ws).
// MFMA orientation: C = W @ X^T  (A = weights, M=channels; B = X^T, N=rows).
//   A-frag: m = lane&15 (channel), k = (lane>>4)*8 + e   (16B global load)
//   B-frag: n = lane&15 (row),     k = (lane>>4)*8 + e   (16B LDS read)
//   C-frag: n = lane&15 (row),     m = (lane>>4)*4 + reg (4 consecutive chans!)
// LDS: X hi @0, X lo @8192 ([64][64] bf16); H hi @16384, H lo @32768
//      ([64][128] bf16). All swizzled byte ^= (row&7)<<4 (16B granular).
// ---------------------------------------------------------------------------
template<int BRANCH, bool MAIN>
__global__ __launch_bounds__(256, 2) void k_pass(
    const float* __restrict__ src, const int* __restrict__ gidx,
    const unsigned short* __restrict__ W1hi, const unsigned short* __restrict__ W1lo,
    const float* __restrict__ cb1, const float* __restrict__ alpha_p,
    const unsigned short* __restrict__ W2hi, const unsigned short* __restrict__ W2lo,
    float* __restrict__ statSlots, float* __restrict__ outp)
{
  extern __shared__ char sm[];
  const int t = threadIdx.x;
  const int lane = t & 63, wid = t >> 6;
  const int l15 = lane & 15, lg = lane >> 4;
  const int blk = blockIdx.x;

  // ---- stage 64 gathered rows: f32 -> bf16 hi/lo, swizzled row-major ----
  #pragma unroll
  for (int i2 = 0; i2 < 4; ++i2){
    int id = i2 * 256 + t;
    int r = id >> 4, fg = id & 15;
    long srow;
    if (BRANCH == 0){
      if (MAIN){                       // paired rows: r<32 first half, else +N
        int pair = blk * 32 + (r & 31);
        int bb = pair >> 17, n = pair & 131071;
        int ii = (r < 32) ? n : (n + 131072);
        srow = (long)bb * 262144 + gidx[ii];
      } else {                         // flat over all B*2N rows
        int g = blk * 64 + r;
        int bb = g >> 18, n = g & 262143;
        srow = (long)bb * 262144 + gidx[n];
      }
    } else {                           // sample branch: B*N rows
      int g = blk * 64 + r;
      int bb = g >> 17, n = g & 131071;
      srow = (long)bb * 65536 + gidx[n];
    }
    float4 x4 = *(const float4*)(src + srow * 64 + fg * 4);
    unsigned short h0 = f2bf(x4.x), h1 = f2bf(x4.y), h2 = f2bf(x4.z), h3 = f2bf(x4.w);
    unsigned short q0 = f2bf(x4.x - bf2f(h0)), q1 = f2bf(x4.y - bf2f(h1)),
                   q2 = f2bf(x4.z - bf2f(h2)), q3 = f2bf(x4.w - bf2f(h3));
    int off = (r * 128 + fg * 8) ^ ((r & 7) << 4);
    uint2 ph, pl;
    ph.x = (unsigned)h0 | ((unsigned)h1 << 16); ph.y = (unsigned)h2 | ((unsigned)h3 << 16);
    pl.x = (unsigned)q0 | ((unsigned)q1 << 16); pl.y = (unsigned)q2 | ((unsigned)q3 << 16);
    *(uint2*)(sm + off)        = ph;
    *(uint2*)(sm + 8192 + off) = pl;
  }
  __syncthreads();

  // ---- W1 A-fragments (wave owns channels wid*32 .. wid*32+31) ----
  uint4 wa1[2][2][2];                  // [ct][kt][hi/lo]
  #pragma unroll
  for (int ct = 0; ct < 2; ++ct)
    #pragma unroll
    for (int kt = 0; kt < 2; ++kt){
      int ch = wid * 32 + ct * 16 + l15;
      int k0 = kt * 32 + lg * 8;
      wa1[ct][kt][0] = *(const uint4*)(W1hi + ch * 64 + k0);
      wa1[ct][kt][1] = *(const uint4*)(W1lo + ch * 64 + k0);
    }

  float ssum[2][4] = {{0,0,0,0},{0,0,0,0}};
  float ssq [2][4] = {{0,0,0,0},{0,0,0,0}};
  float alpha = 0.f;
  if constexpr (MAIN) alpha = alpha_p[0];

  // ---- y1 over 4 row-tiles ----
  #pragma unroll
  for (int nt = 0; nt < 4; ++nt){
    int xr = nt * 16 + l15;
    uint4 bx[2][2];
    #pragma unroll
    for (int kt = 0; kt < 2; ++kt){
      int off = (xr * 128 + (kt * 32 + lg * 8) * 2) ^ ((xr & 7) << 4);
      bx[kt][0] = *(const uint4*)(sm + off);
      bx[kt][1] = *(const uint4*)(sm + 8192 + off);
    }
    #pragma unroll
    for (int ct = 0; ct < 2; ++ct){
      f4_t acc = {0.f, 0.f, 0.f, 0.f};
      #pragma unroll
      for (int kt = 0; kt < 2; ++kt){
        acc = MFMA(wa1[ct][kt][0], bx[kt][0], acc);   // hi*hi
        acc = MFMA(wa1[ct][kt][0], bx[kt][1], acc);   // hi*lo
        acc = MFMA(wa1[ct][kt][1], bx[kt][0], acc);   // lo*hi
      }
      if constexpr (!MAIN){
        #pragma unroll
        for (int j = 0; j < 4; ++j){ ssum[ct][j] += acc[j]; ssq[ct][j] += acc[j] * acc[j]; }
      } else {
        int chb = wid * 32 + ct * 16 + lg * 4;
        float4 cbv = *(const float4*)(cb1 + chb);
        const float* cbf = (const float*)&cbv;
        unsigned short hh[4], hl[4];
        #pragma unroll
        for (int j = 0; j < 4; ++j){
          float y = acc[j] + cbf[j];
          float hv = (y >= 0.f) ? y : alpha * y;      // PReLU
          hh[j] = f2bf(hv); hl[j] = f2bf(hv - bf2f(hh[j]));
        }
        int off = (xr * 256 + chb * 2) ^ ((xr & 7) << 4);
        uint2 ph, pl;
        ph.x = (unsigned)hh[0] | ((unsigned)hh[1] << 16); ph.y = (unsigned)hh[2] | ((unsigned)hh[3] << 16);
        pl.x = (unsigned)hl[0] | ((unsigned)hl[1] << 16); pl.y = (unsigned)hl[2] | ((unsigned)hl[3] << 16);
        *(uint2*)(sm + 16384 + off) = ph;
        *(uint2*)(sm + 32768 + off) = pl;
      }
    }
  }

  if constexpr (!MAIN){
    // per-channel y1 stats -> slot atomics (128 ch, slots1[branch] layout)
    #pragma unroll
    for (int ct = 0; ct < 2; ++ct)
      #pragma unroll
      for (int j = 0; j < 4; ++j){
        ssum[ct][j] = wave16_sum(ssum[ct][j]);
        ssq [ct][j] = wave16_sum(ssq [ct][j]);
      }
    if (l15 == 0){
      int slot = blk & 63;
      #pragma unroll
      for (int ct = 0; ct < 2; ++ct)
        #pragma unroll
        for (int j = 0; j < 4; ++j){
          int ch = wid * 32 + ct * 16 + lg * 4 + j;
          atomicAdd(statSlots + (slot * 2 + 0) * 128 + ch, ssum[ct][j]);
          atomicAdd(statSlots + (slot * 2 + 1) * 128 + ch, ssq [ct][j]);
        }
    }
    return;
  }

  __syncthreads();   // H fully written by all waves

  // ---- W2 A-fragments (wave owns out-channels wid*16 .. wid*16+15) ----
  uint4 wa2[4][2];
  #pragma unroll
  for (int kt = 0; kt < 4; ++kt){
    int oc = wid * 16 + l15;
    int k0 = kt * 32 + lg * 8;
    wa2[kt][0] = *(const uint4*)(W2hi + oc * 128 + k0);
    wa2[kt][1] = *(const uint4*)(W2lo + oc * 128 + k0);
  }

  float tsum[4] = {0,0,0,0}, tsq[4] = {0,0,0,0};
  f4_t keep0 = {0,0,0,0}, keep1 = {0,0,0,0};

  #pragma unroll
  for (int nt = 0; nt < 4; ++nt){
    int xr = nt * 16 + l15;
    f4_t acc = {0.f, 0.f, 0.f, 0.f};
    #pragma unroll
    for (int kt = 0; kt < 4; ++kt){
      int off = (xr * 256 + (kt * 32 + lg * 8) * 2) ^ ((xr & 7) << 4);
      uint4 bh = *(const uint4*)(sm + 16384 + off);
      uint4 bl = *(const uint4*)(sm + 32768 + off);
      acc = MFMA(wa2[kt][0], bh, acc);
      acc = MFMA(wa2[kt][0], bl, acc);
      acc = MFMA(wa2[kt][1], bh, acc);
    }
    #pragma unroll
    for (int j = 0; j < 4; ++j){ tsum[j] += acc[j]; tsq[j] += acc[j] * acc[j]; }

    if constexpr (BRANCH == 0){
      // rows 0..31 = first pair halves (kept), rows 32..63 = partners (max+store)
      if (nt == 0) keep0 = acc;
      else if (nt == 1) keep1 = acc;
      else {
        f4_t kp = (nt == 2) ? keep0 : keep1;
        float4 st;
        st.x = fmaxf(kp[0], acc[0]); st.y = fmaxf(kp[1], acc[1]);
        st.z = fmaxf(kp[2], acc[2]); st.w = fmaxf(kp[3], acc[3]);
        long pair = (long)blk * 32 + (nt - 2) * 16 + l15;
        *(float4*)(outp + pair * 64 + wid * 16 + lg * 4) = st;    // raw maxpair
      }
    } else {
      long g = (long)blk * 64 + xr;
      float4 st; st.x = acc[0]; st.y = acc[1]; st.z = acc[2]; st.w = acc[3];
      *(float4*)(outp + g * 64 + wid * 16 + lg * 4) = st;         // raw y2s
    }
  }

  // per-channel y2 stats -> slot atomics (64 ch, slots2[branch] layout)
  #pragma unroll
  for (int j = 0; j < 4; ++j){ tsum[j] = wave16_sum(tsum[j]); tsq[j] = wave16_sum(tsq[j]); }
  if (l15 == 0){
    int slot = blk & 63;
    #pragma unroll
    for (int j = 0; j < 4; ++j){
      int ch = wid * 16 + lg * 4 + j;
      atomicAdd(statSlots + (slot * 2 + 0) * 64 + ch, tsum[j]);
      atomicAdd(statSlots + (slot * 2 + 1) * 64 + ch, tsq[j]);
    }
  }
}

// ---------------------------------------------------------------------------
// k_fold1: reduce stats1 slots -> m1,v1 -> fold BN scale into W1 (hi/lo) + b1'.
// One block per branch.
// ---------------------------------------------------------------------------
__global__ void k_fold1(const float* __restrict__ slots1,
                        const float* __restrict__ g1, const float* __restrict__ be1,
                        const float* __restrict__ sg1, const float* __restrict__ sbe1,
                        const float* __restrict__ W1, const float* __restrict__ sW1,
                        unsigned short* __restrict__ W1fhi, unsigned short* __restrict__ W1flo,
                        float* __restrict__ cb1)
{
  int br = blockIdx.x, t = threadIdx.x;
  const float* sl = slots1 + br * 16384;          // [64][2][128]
  __shared__ float red[256];
  __shared__ float s1buf[128];
  float v = 0.f;
  for (int s = 0; s < 64; ++s) v += sl[s * 256 + t];
  red[t] = v;
  __syncthreads();
  if (t < 128){
    float R  = br ? 524288.f : 1048576.f;
    float m  = red[t] / R;
    float q  = red[128 + t] / R;
    float var = q - m * m;
    const float* g  = br ? sg1  : g1;
    const float* be = br ? sbe1 : be1;
    float s1 = g[t] * rsqrtf(var + 1e-5f);
    s1buf[t] = s1;
    cb1[br * 128 + t] = be[t] - m * s1;           // bias (b1 cancels in BN)
  }
  __syncthreads();
  const float* Wsrc = br ? sW1 : W1;
  for (int e = t; e < 8192; e += 256){
    int ch = e >> 6;
    float w = Wsrc[e] * s1buf[ch];
    unsigned short h = f2bf(w);
    W1fhi[br * 8192 + e] = h;
    W1flo[br * 8192 + e] = f2bf(w - bf2f(h));
  }
}

// ---------------------------------------------------------------------------
// k_fold2: reduce stats2 slots -> per-channel output affine (s2, b2'). 1 block.
// ---------------------------------------------------------------------------
__global__ void k_fold2(const float* __restrict__ slots2,
                        const float* __restrict__ g2, const float* __restrict__ be2,
                        const float* __restrict__ sg2, const float* __restrict__ sbe2,
                        float* __restrict__ aff)
{
  int t = threadIdx.x;                    // t = br*128 + stat*64 + ch
  int br = t >> 7, rem = t & 127;
  const float* sl = slots2 + br * 8192;   // [64][2][64]
  float v = 0.f;
  for (int s = 0; s < 64; ++s) v += sl[s * 128 + rem];
  __shared__ float red[256];
  red[t] = v;
  __syncthreads();
  if (t < 128){
    int br2 = t >> 6, ch = t & 63;
    float R = br2 ? 524288.f : 1048576.f;
    float m = red[br2 * 128 + ch] / R;
    float q = red[br2 * 128 + 64 + ch] / R;
    float var = q - m * m;
    const float* g  = br2 ? sg2  : g2;
    const float* be = br2 ? sbe2 : be2;
    float s2 = g[ch] * rsqrtf(var + 1e-5f);
    aff[br2 * 128 + ch]      = s2;
    aff[br2 * 128 + 64 + ch] = be[ch] - m * s2;
  }
}

// ---------------------------------------------------------------------------
// k_final: out = replaced ? affine_s(y2s) : affine_m(maxpair). Elementwise f4.
// ---------------------------------------------------------------------------
__global__ void k_final(const float* __restrict__ y2s, const int* __restrict__ repl,
                        const float* __restrict__ aff, float* __restrict__ out, long n4)
{
  long i = (long)blockIdx.x * 256 + threadIdx.x;
  long stride = (long)gridDim.x * 256;
  for (; i < n4; i += stride){
    long e = i * 4;
    int ch = (int)(e & 63);
    float4 mp = *(const float4*)(out + e);
    float4 ys = *(const float4*)(y2s + e);
    int4   rp = *(const int4*)(repl + e);
    float4 s0 = *(const float4*)(aff + ch);          // main scale
    float4 b0 = *(const float4*)(aff + 64 + ch);     // main bias
    float4 s1 = *(const float4*)(aff + 128 + ch);    // sample scale
    float4 b1 = *(const float4*)(aff + 192 + ch);    // sample bias
    float4 r;
    r.x = rp.x ? (ys.x * s1.x + b1.x) : (mp.x * s0.x + b0.x);
    r.y = rp.y ? (ys.y * s1.y + b1.y) : (mp.y * s0.y + b0.y);
    r.z = rp.z ? (ys.z * s1.z + b1.z) : (mp.z * s0.z + b0.z);
    r.w = rp.w ? (ys.w * s1.w + b1.w) : (mp.w * s0.w + b0.w);
    *(float4*)(out + e) = r;
  }
}

// ---------------------------------------------------------------------------
extern "C" void kernel_launch(void* const* d_in, const int* in_sizes, int n_in,
                              void* d_out, int out_size, void* d_ws, size_t ws_size,
                              hipStream_t stream)
{
  const float* last   = (const float*)d_in[0];
  const float* sample = (const float*)d_in[1];
  const float* W1     = (const float*)d_in[2];
  const float* g1     = (const float*)d_in[4];
  const float* be1    = (const float*)d_in[5];
  const float* a1     = (const float*)d_in[6];
  const float* W2     = (const float*)d_in[7];
  const float* g2     = (const float*)d_in[9];
  const float* be2    = (const float*)d_in[10];
  const float* sW1    = (const float*)d_in[11];
  const float* sg1    = (const float*)d_in[13];
  const float* sbe1   = (const float*)d_in[14];
  const float* sa1    = (const float*)d_in[15];
  const float* sW2    = (const float*)d_in[16];
  const float* sg2    = (const float*)d_in[18];
  const float* sbe2   = (const float*)d_in[19];
  const int* child_lr = (const int*)d_in[20];
  const int* child_s  = (const int*)d_in[21];
  const int* repl     = (const int*)d_in[22];   // ASSUMED int32 (bool->int)
  float* out = (float*)d_out;

  // ---- workspace carve (needs ~134.5 MB) ----
  char* w = (char*)d_ws;
  float* y2s = (float*)w;                                       // 134217728 B
  unsigned short* W1rhi = (unsigned short*)(w + 134217728);     // [2][8192]
  unsigned short* W1rlo = W1rhi + 16384;
  unsigned short* W2rhi = W1rlo + 16384;
  unsigned short* W2rlo = W2rhi + 16384;
  unsigned short* W1fhi = W2rlo + 16384;
  unsigned short* W1flo = W1fhi + 16384;
  float* cb1    = (float*)(W1flo + 16384);   // [2][128]
  float* aff    = cb1 + 256;                 // [2][2][64]
  float* slots1 = aff + 256;                 // [2][64][2][128] = 32768 f
  float* slots2 = slots1 + 32768;            // [2][64][2][64]  = 16384 f

  k_init<<<320, 256, 0, stream>>>(W1, sW1, W2, sW2, W1rhi, W1rlo, W2rhi, W2rlo,
                                  slots1, slots2);

  // stats1: y1_raw stats per channel (both branches)
  k_pass<0, false><<<16384, 256, 16384, stream>>>(
      last, child_lr, W1rhi, W1rlo, nullptr, nullptr, nullptr, nullptr,
      slots1, nullptr);
  k_pass<1, false><<<8192, 256, 16384, stream>>>(
      sample, child_s, W1rhi + 8192, W1rlo + 8192, nullptr, nullptr, nullptr, nullptr,
      slots1 + 16384, nullptr);

  k_fold1<<<2, 256, 0, stream>>>(slots1, g1, be1, sg1, sbe1, W1, sW1,
                                 W1fhi, W1flo, cb1);

  // main pass: h -> raw y2 (+stats); br0 writes pair-max into d_out, br1 -> ws
  k_pass<0, true><<<16384, 256, 49152, stream>>>(
      last, child_lr, W1fhi, W1flo, cb1, a1, W2rhi, W2rlo,
      slots2, out);
  k_pass<1, true><<<8192, 256, 49152, stream>>>(
      sample, child_s, W1fhi + 8192, W1flo + 8192, cb1 + 128, sa1,
      W2rhi + 8192, W2rlo + 8192, slots2 + 8192, y2s);

  k_fold2<<<1, 256, 0, stream>>>(slots2, g2, be2, sg2, sbe2, aff);

  k_final<<<4096, 256, 0, stream>>>(y2s, repl, aff, out, 8388608L);
}